// Round 17
// baseline (215.688 us; speedup 1.0000x reference)
//
#include <hip/hip_runtime.h>
#include <math.h>

#define NB 8
#define NCH 30
#define LL 16384
#define N1 6000
#define N2 4914
#define NCLS 5
#define KLIM 8192
#define ATT_K 13

typedef float f32x4 __attribute__((ext_vector_type(4)));

__device__ __forceinline__ unsigned fkey(float f) {
  unsigned u = __float_as_uint(f);
  unsigned m = (unsigned)(((int)u) >> 31) | 0x80000000u;
  return u ^ m;  // order-preserving float->uint
}
__device__ __forceinline__ float sigmoidf(float x) { return 1.f / (1.f + expf(-x)); }

// ---- K1: per-(b,c) mean pool over HxH = 16384 ----
__global__ void k_pool(const float* __restrict__ adj, float* __restrict__ pooled) {
  int bc = blockIdx.x;                       // 0..239
  const float* p = adj + (size_t)bc * LL;
  int tid = threadIdx.x;
  float s = 0.f;
  #pragma unroll
  for (int it = 0; it < LL / (256 * 4); ++it) {
    float4 v = *(const float4*)(p + it * 1024 + tid * 4);
    s += v.x + v.y + v.z + v.w;
  }
  #pragma unroll
  for (int m = 1; m < 64; m <<= 1) s += __shfl_xor(s, m);
  __shared__ float red[4];
  if ((tid & 63) == 0) red[tid >> 6] = s;
  __syncthreads();
  if (tid == 0) pooled[bc] = (red[0] + red[1] + red[2] + red[3]) * (1.f / (float)LL);
}

// ---- K2 (fused eca+wsum) ----
__global__ void k_wsum(const float* __restrict__ adj, const float* __restrict__ pooled,
                       const float* __restrict__ ew, float* __restrict__ y,
                       float* __restrict__ pmm, float* __restrict__ band_out) {
  int blk = blockIdx.x;                       // b*16 + tile
  int b = blk >> 4, tile = blk & 15;
  int tid = threadIdx.x;
  __shared__ float sc[NCH];
  if (tid < NCH) {
    int c = tid;
    const float* p = pooled + b * NCH;
    float s = ew[1] * p[c];
    if (c > 0)       s += ew[0] * p[c - 1];
    if (c < NCH - 1) s += ew[2] * p[c + 1];
    float scv = sigmoidf(s);
    sc[c] = scv;
    if (tile == 0) band_out[b * NCH + c] = scv;
  }
  __syncthreads();
  int j = tile * 1024 + tid * 4;
  const float* base = adj + (size_t)b * NCH * LL + j;
  float4 acc = {0.f, 0.f, 0.f, 0.f};
  #pragma unroll
  for (int c = 0; c < NCH; ++c) {
    float4 v = *(const float4*)(base + (size_t)c * LL);
    float s = sc[c];
    acc.x += v.x * s; acc.y += v.y * s; acc.z += v.z * s; acc.w += v.w * s;
  }
  *(float4*)(y + b * LL + j) = acc;
  float mn = fminf(fminf(acc.x, acc.y), fminf(acc.z, acc.w));
  float mx = fmaxf(fmaxf(acc.x, acc.y), fmaxf(acc.z, acc.w));
  #pragma unroll
  for (int m = 1; m < 64; m <<= 1) {
    mn = fminf(mn, __shfl_xor(mn, m));
    mx = fmaxf(mx, __shfl_xor(mx, m));
  }
  __shared__ float wmn[4], wmx[4];
  if ((tid & 63) == 0) { wmn[tid >> 6] = mn; wmx[tid >> 6] = mx; }
  __syncthreads();
  if (tid == 0) {
    mn = fminf(fminf(wmn[0], wmn[1]), fminf(wmn[2], wmn[3]));
    mx = fmaxf(fmaxf(wmx[0], wmx[1]), fmaxf(wmx[2], wmx[3]));
    pmm[blk * 2 + 0] = mn; pmm[blk * 2 + 1] = mx;
  }
}

// ---- K3 (fused): normalize -> conv13 -> exact top-8192 select -> scatter sparse ----
// DIAGNOSTIC: body runs TWICE (idempotent). dur_total - 173.8us = T_selfuse.
__global__ __launch_bounds__(1024) void k_selfuse(const float* __restrict__ y,
                                                  const float* __restrict__ pmm,
                                                  const float* __restrict__ w,
                                                  float* __restrict__ sp) {
  int b = blockIdx.x;
  int tid = threadIdx.x;
  int wave = tid >> 6, lane = tid & 63;
  extern __shared__ float vsh[];            // 16896 floats, idx(j) = j + (j>>5)
  __shared__ float wl[ATT_K];
  __shared__ int redw[16][3];
  __shared__ int ctot[3];
  __shared__ int wtot[16];

  for (int rep = 0; rep < 2; ++rep) {
    __syncthreads();
    if (tid < ATT_K) wl[tid] = w[tid];

    float mn = pmm[b * 32], mx = pmm[b * 32 + 1];
    #pragma unroll
    for (int t = 1; t < 16; ++t) {
      mn = fminf(mn, pmm[b * 32 + t * 2]);
      mx = fmaxf(mx, pmm[b * 32 + t * 2 + 1]);
    }
    float inv = 1.f / (mx - mn);

    const float* yb = y + b * LL;
    #pragma unroll
    for (int c = 0; c < 4; ++c) {
      int i = c * 4096 + tid * 4;
      float4 t4 = *(const float4*)(yb + i);
      int p0 = i + (i >> 5);
      vsh[p0 + 0] = (t4.x - mn) * inv;
      vsh[p0 + 1] = (t4.y - mn) * inv;
      vsh[p0 + 2] = (t4.z - mn) * inv;
      vsh[p0 + 3] = (t4.w - mn) * inv;
    }
    __syncthreads();

    int e = tid * 16;
    unsigned kk[16];
    {
      float v28[28];
      #pragma unroll
      for (int i = 0; i < 28; ++i) {
        int j = e - 6 + i;
        v28[i] = (j >= 0 && j < LL) ? vsh[j + (j >> 5)] : 0.f;
      }
      #pragma unroll
      for (int i = 0; i < 16; ++i) {
        float acc = 0.f;
        #pragma unroll
        for (int k = 0; k < ATT_K; ++k) acc += v28[i + k] * wl[k];
        kk[i] = fkey(acc);
      }
    }

    unsigned p = 0; int need = KLIM;
    for (int pass = 0; pass < 16; ++pass) {
      int sh = 30 - pass * 2;
      unsigned himask = (pass == 0) ? 0u : (0xFFFFFFFFu << (sh + 2));
      int c3 = 0, c2 = 0, c1 = 0;
      #pragma unroll
      for (int i = 0; i < 16; ++i) {
        unsigned k2 = kk[i];
        if ((k2 & himask) == p) {
          unsigned bk = (k2 >> sh) & 3u;
          c3 += (bk == 3); c2 += (bk == 2); c1 += (bk == 1);
        }
      }
      #pragma unroll
      for (int m = 1; m < 64; m <<= 1) {
        c3 += __shfl_xor(c3, m); c2 += __shfl_xor(c2, m); c1 += __shfl_xor(c1, m);
      }
      if (lane == 0) { redw[wave][0] = c3; redw[wave][1] = c2; redw[wave][2] = c1; }
      __syncthreads();
      if (wave == 0) {
        int a0 = 0, a1 = 0, a2 = 0;
        if (lane < 16) { a0 = redw[lane][0]; a1 = redw[lane][1]; a2 = redw[lane][2]; }
        #pragma unroll
        for (int m = 1; m < 16; m <<= 1) {
          a0 += __shfl_xor(a0, m); a1 += __shfl_xor(a1, m); a2 += __shfl_xor(a2, m);
        }
        if (lane == 0) { ctot[0] = a0; ctot[1] = a1; ctot[2] = a2; }
      }
      __syncthreads();
      int C3 = ctot[0], C2 = ctot[1], C1 = ctot[2];
      if (C3 >= need)                { p |= 3u << sh; }
      else if (C3 + C2 >= need)      { p |= 2u << sh; need -= C3; }
      else if (C3 + C2 + C1 >= need) { p |= 1u << sh; need -= C3 + C2; }
      else                           { need -= C3 + C2 + C1; }
    }

    int cnt = 0;
    #pragma unroll
    for (int i = 0; i < 16; ++i) cnt += (kk[i] == p);
    int pre = cnt;
    #pragma unroll
    for (int m = 1; m < 64; m <<= 1) {
      int t = __shfl_up(pre, m);
      if (lane >= m) pre += t;
    }
    if (lane == 63) wtot[wave] = pre;
    __syncthreads();
    int base = 0;
    for (int t = 0; t < 16; ++t) if (t < wave) base += wtot[t];
    int rank = base + pre - cnt;

    float v28[28];
    #pragma unroll
    for (int i = 0; i < 28; ++i) {
      int j = e - 6 + i;
      v28[i] = (j >= 0 && j < LL) ? vsh[j + (j >> 5)] : 0.f;
    }
    float outv[16];
    #pragma unroll
    for (int i = 0; i < 16; ++i) {
      float acc = 0.f;
      #pragma unroll
      for (int k = 0; k < ATT_K; ++k) acc += v28[i + k] * wl[k];
      bool sel;
      if (kk[i] > p) sel = true;
      else if (kk[i] == p) { sel = (rank < need); rank++; }
      else sel = false;
      outv[i] = sel ? v28[i + 6] * (sigmoidf(acc) + 1.f) : 0.f;
    }
    float* spb = sp + b * LL + e;
    #pragma unroll
    for (int q = 0; q < 4; ++q)
      *(f32x4*)(spb + q * 4) = *(f32x4*)(outv + q * 4);
  }
}

// ---- K4: split-K GEMM1 partials (R8 body, unchanged) ----
__global__ __launch_bounds__(1024, 4) void k_gemm1(const float* __restrict__ W1,
                                                   const float* __restrict__ sp,
                                                   float* __restrict__ p1) {
  __shared__ float sps[8][2048];            // 64 KB
  int bid = blockIdx.x;
  int s = bid & 7, g = bid >> 3;            // split, row-group
  int tid = threadIdx.x, wave = tid >> 6, lane = tid & 63;
  #pragma unroll
  for (int i = 0; i < 4; ++i) {
    int idx = i * 1024 + tid;               // f32x4 index 0..4095
    int bb = idx >> 9, off = (idx & 511) * 4;
    *(f32x4*)&sps[bb][off] = *(const f32x4*)(sp + (size_t)bb * LL + s * 2048 + off);
  }
  __syncthreads();
  int r0 = g * 94;
  int nr = N1 - r0; if (nr > 94) nr = 94;   // always even (94 or 78)
  int npair = nr >> 1;
  for (int p = wave; p < npair; p += 16) {
    int rA = r0 + p * 2;
    const float* wpA = W1 + (size_t)rA * LL + s * 2048;
    const float* wpB = wpA + LL;
    float acc0[8], acc1[8];
    #pragma unroll
    for (int bb = 0; bb < 8; ++bb) { acc0[bb] = 0.f; acc1[bb] = 0.f; }
    #pragma unroll 2
    for (int it = 0; it < 8; ++it) {
      int k0 = it * 256 + lane * 4;
      f32x4 wA = __builtin_nontemporal_load((const f32x4*)(wpA + k0));
      f32x4 wB = __builtin_nontemporal_load((const f32x4*)(wpB + k0));
      #pragma unroll
      for (int bb = 0; bb < 8; ++bb) {
        f32x4 s4 = *(const f32x4*)&sps[bb][k0];
        acc0[bb] += wA.x * s4.x + wA.y * s4.y + wA.z * s4.z + wA.w * s4.w;
        acc1[bb] += wB.x * s4.x + wB.y * s4.y + wB.z * s4.z + wB.w * s4.w;
      }
    }
    #pragma unroll
    for (int bb = 0; bb < 8; ++bb) {
      float a0 = acc0[bb], a1 = acc1[bb];
      #pragma unroll
      for (int m = 1; m < 64; m <<= 1) {
        a0 += __shfl_xor(a0, m);
        a1 += __shfl_xor(a1, m);
      }
      if (lane == 0) {
        p1[(size_t)(s * 8 + bb) * N1 + rA]     = a0;
        p1[(size_t)(s * 8 + bb) * N1 + rA + 1] = a1;
      }
    }
  }
}

// ---- K5: split-K GEMM2 partials (R8 body; 30-row groups, 3x164 grid) ----
__global__ __launch_bounds__(1024, 4) void k_gemm2(const float* __restrict__ W2,
                                                   const float* __restrict__ p1,
                                                   const float* __restrict__ b1,
                                                   float* __restrict__ p2) {
  __shared__ float hs[8][2048];             // 64 KB
  int bid = blockIdx.x;
  int s = bid / 164, g = bid % 164;
  int ks = s * 2048;
  int klen = (s == 2) ? (N1 - 4096) : 2048; // 1904 for last split
  int tid = threadIdx.x, wave = tid >> 6, lane = tid & 63;
  #pragma unroll
  for (int i = 0; i < 4; ++i) {
    int idx = i * 1024 + tid;               // 0..4095
    int bb = idx >> 9, off = (idx & 511) * 4;
    f32x4 v = {0.f, 0.f, 0.f, 0.f};
    if (off < klen) {
      int j = ks + off;
      #pragma unroll
      for (int q = 0; q < 8; ++q)
        v += *(const f32x4*)(p1 + (size_t)(q * 8 + bb) * N1 + j);
      v += *(const f32x4*)(b1 + j);
    }
    *(f32x4*)&hs[bb][off] = v;
  }
  __syncthreads();
  int r0 = g * 30;
  int nr = N2 - r0; if (nr > 30) nr = 30; if (nr < 0) nr = 0;  // even (30/24)
  int npair = nr >> 1;
  for (int p = wave; p < npair; p += 16) {
    int rA = r0 + p * 2;
    const float* wpA = W2 + (size_t)rA * N1 + ks;
    const float* wpB = wpA + N1;
    float acc0[8], acc1[8];
    #pragma unroll
    for (int bb = 0; bb < 8; ++bb) { acc0[bb] = 0.f; acc1[bb] = 0.f; }
    #pragma unroll 2
    for (int it = 0; it < 8; ++it) {
      int k0 = it * 256 + lane * 4;
      // hs is zero beyond klen, so products vanish; W read stays in-page.
      f32x4 wA = __builtin_nontemporal_load((const f32x4*)(wpA + k0));
      f32x4 wB = __builtin_nontemporal_load((const f32x4*)(wpB + k0));
      #pragma unroll
      for (int bb = 0; bb < 8; ++bb) {
        f32x4 s4 = *(const f32x4*)&hs[bb][k0];
        acc0[bb] += wA.x * s4.x + wA.y * s4.y + wA.z * s4.z + wA.w * s4.w;
        acc1[bb] += wB.x * s4.x + wB.y * s4.y + wB.z * s4.z + wB.w * s4.w;
      }
    }
    #pragma unroll
    for (int bb = 0; bb < 8; ++bb) {
      float a0 = acc0[bb], a1 = acc1[bb];
      #pragma unroll
      for (int m = 1; m < 64; m <<= 1) {
        a0 += __shfl_xor(a0, m);
        a1 += __shfl_xor(a1, m);
      }
      if (lane == 0) {
        p2[(size_t)(s * 8 + bb) * N2 + rA]     = a0;
        p2[(size_t)(s * 8 + bb) * N2 + rA + 1] = a1;
      }
    }
  }
}

// ---- K6: t[b,m] = sum_n h2[b,n]*Wc1[m,n], h2 reconstructed from 3 partials + b2 ----
__global__ void k_cls1(const float* __restrict__ p2, const float* __restrict__ b2,
                       const float* __restrict__ Wc1, float* __restrict__ t) {
  int bid = blockIdx.x; int b = bid >> 5, m = bid & 31;
  int tid = threadIdx.x;
  const float* wm = Wc1 + m * N2;
  float s = 0.f;
  for (int j = tid; j < N2; j += 256) {
    float hv = p2[(size_t)(0 * 8 + b) * N2 + j]
             + p2[(size_t)(1 * 8 + b) * N2 + j]
             + p2[(size_t)(2 * 8 + b) * N2 + j] + b2[j];
    s += hv * wm[j];
  }
  #pragma unroll
  for (int mm = 1; mm < 64; mm <<= 1) s += __shfl_xor(s, mm);
  __shared__ float red[4];
  if ((tid & 63) == 0) red[tid >> 6] = s;
  __syncthreads();
  if (tid == 0) t[b * 32 + m] = red[0] + red[1] + red[2] + red[3];
}

// ---- K7: logits = t @ Wc2^T ; log_softmax ----
__global__ void k_final(const float* __restrict__ t, const float* __restrict__ Wc2,
                        float* __restrict__ out) {
  int b = threadIdx.x;
  if (b < NB) {
    float lg[NCLS];
    #pragma unroll
    for (int k = 0; k < NCLS; ++k) {
      float s = 0.f;
      #pragma unroll
      for (int m = 0; m < 32; ++m) s += t[b * 32 + m] * Wc2[k * 32 + m];
      lg[k] = s;
    }
    float mx = lg[0];
    #pragma unroll
    for (int k = 1; k < NCLS; ++k) mx = fmaxf(mx, lg[k]);
    float se = 0.f;
    #pragma unroll
    for (int k = 0; k < NCLS; ++k) se += expf(lg[k] - mx);
    float lse = logf(se);
    #pragma unroll
    for (int k = 0; k < NCLS; ++k) out[b * NCLS + k] = lg[k] - mx - lse;
  }
}

extern "C" void kernel_launch(void* const* d_in, const int* in_sizes, int n_in,
                              void* d_out, int out_size, void* d_ws, size_t ws_size,
                              hipStream_t stream) {
  const float* adj   = (const float*)d_in[0];
  const float* eca_w = (const float*)d_in[1];
  const float* att_w = (const float*)d_in[2];
  const float* W1    = (const float*)d_in[3];
  const float* b1    = (const float*)d_in[4];
  const float* W2    = (const float*)d_in[5];
  const float* b2    = (const float*)d_in[6];
  const float* Wc1   = (const float*)d_in[7];
  const float* Wc2   = (const float*)d_in[8];
  float* out = (float*)d_out;
  float* ws  = (float*)d_ws;

  float* pooled = ws;              // 240
  float* pmm    = ws + 512;        // 256
  float* tbuf   = ws + 768;        // 256
  float* y      = ws + 1024;       // 131072
  float* sp     = y  + NB * LL;    // 131072
  float* p1     = sp + NB * LL;    // 8*8*6000 = 384000
  float* p2     = p1 + 384000;     // 3*8*4914 = 117936

  k_pool   <<<NB * NCH, 256, 0, stream>>>(adj, pooled);
  k_wsum   <<<NB * 16, 256, 0, stream>>>(adj, pooled, eca_w, y, pmm, out + NB * NCLS);
  k_selfuse<<<NB, 1024, 16896 * sizeof(float), stream>>>(y, pmm, att_w, sp);
  k_gemm1  <<<8 * 64, 1024, 0, stream>>>(W1, sp, p1);
  k_gemm2  <<<3 * 164, 1024, 0, stream>>>(W2, p1, b1, p2);
  k_cls1   <<<NB * 32, 256, 0, stream>>>(p2, b2, Wc1, tbuf);
  k_final  <<<1, 64, 0, stream>>>(tbuf, Wc2, out);
}

// Round 18
// 150.424 us; speedup vs baseline: 1.4339x; 1.4339x over previous
//
#include <hip/hip_runtime.h>
#include <math.h>

#define NB 8
#define NCH 30
#define LL 16384
#define N1 6000
#define N2 4914
#define NCLS 5
#define KLIM 8192
#define ATT_K 13

typedef float f32x4 __attribute__((ext_vector_type(4)));

__device__ __forceinline__ unsigned fkey(float f) {
  unsigned u = __float_as_uint(f);
  unsigned m = (unsigned)(((int)u) >> 31) | 0x80000000u;
  return u ^ m;  // order-preserving float->uint
}
__device__ __forceinline__ float sigmoidf(float x) { return 1.f / (1.f + expf(-x)); }

// ---- K1: per-(b,c) mean pool over HxH = 16384 ----
__global__ void k_pool(const float* __restrict__ adj, float* __restrict__ pooled) {
  int bc = blockIdx.x;                       // 0..239
  const float* p = adj + (size_t)bc * LL;
  int tid = threadIdx.x;
  float s = 0.f;
  #pragma unroll
  for (int it = 0; it < LL / (256 * 4); ++it) {
    float4 v = *(const float4*)(p + it * 1024 + tid * 4);
    s += v.x + v.y + v.z + v.w;
  }
  #pragma unroll
  for (int m = 1; m < 64; m <<= 1) s += __shfl_xor(s, m);
  __shared__ float red[4];
  if ((tid & 63) == 0) red[tid >> 6] = s;
  __syncthreads();
  if (tid == 0) pooled[bc] = (red[0] + red[1] + red[2] + red[3]) * (1.f / (float)LL);
}

// ---- K2 (fused eca+wsum); also zeroes ghist (16384 ints over 128 blocks) ----
__global__ void k_wsum(const float* __restrict__ adj, const float* __restrict__ pooled,
                       const float* __restrict__ ew, float* __restrict__ y,
                       float* __restrict__ pmm, float* __restrict__ band_out,
                       int* __restrict__ ghist) {
  int blk = blockIdx.x;                       // b*16 + tile
  int b = blk >> 4, tile = blk & 15;
  int tid = threadIdx.x;
  if (tid >= 128) ghist[blk * 128 + (tid - 128)] = 0;
  __shared__ float sc[NCH];
  if (tid < NCH) {
    int c = tid;
    const float* p = pooled + b * NCH;
    float s = ew[1] * p[c];
    if (c > 0)       s += ew[0] * p[c - 1];
    if (c < NCH - 1) s += ew[2] * p[c + 1];
    float scv = sigmoidf(s);
    sc[c] = scv;
    if (tile == 0) band_out[b * NCH + c] = scv;
  }
  __syncthreads();
  int j = tile * 1024 + tid * 4;
  const float* base = adj + (size_t)b * NCH * LL + j;
  float4 acc = {0.f, 0.f, 0.f, 0.f};
  #pragma unroll
  for (int c = 0; c < NCH; ++c) {
    float4 v = *(const float4*)(base + (size_t)c * LL);
    float s = sc[c];
    acc.x += v.x * s; acc.y += v.y * s; acc.z += v.z * s; acc.w += v.w * s;
  }
  *(float4*)(y + b * LL + j) = acc;
  float mn = fminf(fminf(acc.x, acc.y), fminf(acc.z, acc.w));
  float mx = fmaxf(fmaxf(acc.x, acc.y), fmaxf(acc.z, acc.w));
  #pragma unroll
  for (int m = 1; m < 64; m <<= 1) {
    mn = fminf(mn, __shfl_xor(mn, m));
    mx = fmaxf(mx, __shfl_xor(mx, m));
  }
  __shared__ float wmn[4], wmx[4];
  if ((tid & 63) == 0) { wmn[tid >> 6] = mn; wmx[tid >> 6] = mx; }
  __syncthreads();
  if (tid == 0) {
    mn = fminf(fminf(wmn[0], wmn[1]), fminf(wmn[2], wmn[3]));
    mx = fmaxf(fmaxf(wmx[0], wmx[1]), fmaxf(wmx[2], wmx[3]));
    pmm[blk * 2 + 0] = mn; pmm[blk * 2 + 1] = mx;
  }
}

// ---- K3a: normalize + conv13 -> raw scores sv ; 11-bit histogram -> ghist ----
// 64 blocks (8 samples x 8 chunks of 2048), 256 threads.
__global__ __launch_bounds__(256) void k_score(const float* __restrict__ y,
                                               const float* __restrict__ pmm,
                                               const float* __restrict__ w,
                                               float* __restrict__ sv,
                                               int* __restrict__ ghist) {
  int bid = blockIdx.x;
  int b = bid >> 3, c = bid & 7;
  int tid = threadIdx.x;
  __shared__ float le[2124];                // 2060 + pad (i + (i>>5))
  __shared__ float wl[ATT_K];
  __shared__ int h[2048];
  if (tid < ATT_K) wl[tid] = w[tid];
  #pragma unroll
  for (int q = 0; q < 8; ++q) h[q * 256 + tid] = 0;

  float mn = pmm[b * 32], mx = pmm[b * 32 + 1];
  #pragma unroll
  for (int t = 1; t < 16; ++t) {
    mn = fminf(mn, pmm[b * 32 + t * 2]);
    mx = fmaxf(mx, pmm[b * 32 + t * 2 + 1]);
  }
  float inv = 1.f / (mx - mn);

  for (int i = tid; i < 2060; i += 256) {
    int j = c * 2048 - 6 + i;
    le[i + (i >> 5)] = (j >= 0 && j < LL) ? (y[b * LL + j] - mn) * inv : 0.f;
  }
  __syncthreads();

  int e = tid * 8;                          // local element base
  float acc[8];
  #pragma unroll
  for (int i = 0; i < 8; ++i) {
    float a = 0.f;
    #pragma unroll
    for (int k = 0; k < ATT_K; ++k) {
      int l = e + i + k;
      a += le[l + (l >> 5)] * wl[k];
    }
    acc[i] = a;
  }
  float* svp = sv + b * LL + c * 2048 + e;
  *(f32x4*)(svp)     = (f32x4){acc[0], acc[1], acc[2], acc[3]};
  *(f32x4*)(svp + 4) = (f32x4){acc[4], acc[5], acc[6], acc[7]};
  #pragma unroll
  for (int i = 0; i < 8; ++i)
    atomicAdd(&h[fkey(acc[i]) >> 21], 1);
  __syncthreads();
  #pragma unroll
  for (int q = 0; q < 8; ++q) {
    int bin = q * 256 + tid;
    int cv = h[bin];
    if (cv) atomicAdd(&ghist[b * 2048 + bin], cv);
  }
}

// descending segmented scan over NBINS-bin LDS histogram; picks the bucket where
// cumulative-from-top crosses `need`. selres[0]=bin, selres[1]=count above bucket.
template <int NBINS>
__device__ __forceinline__ void desc_pick(int* h, int* scn, int* segtot, int* segbase,
                                          int* selres, int need, int wave, int lane) {
  const int NSEG = NBINS / 64;
  for (int s = wave; s < NSEG; s += 16) {
    int d = s * 64 + lane;
    int bin = NBINS - 1 - d;
    int inc = h[bin];
    #pragma unroll
    for (int m = 1; m < 64; m <<= 1) {
      int t = __shfl_up(inc, m);
      if (lane >= m) inc += t;
    }
    scn[d] = inc;
    if (lane == 63) segtot[s] = inc;
  }
  __syncthreads();
  if (wave == 0) {
    int v = (lane < NSEG) ? segtot[lane] : 0;
    int inc = v;
    #pragma unroll
    for (int m = 1; m < 32; m <<= 1) {
      int t = __shfl_up(inc, m);
      if (lane >= m) inc += t;
    }
    if (lane < NSEG) segbase[lane] = inc - v;   // exclusive
  }
  __syncthreads();
  for (int s = wave; s < NSEG; s += 16) {
    int d = s * 64 + lane;
    int bin = NBINS - 1 - d;
    int incl = segbase[s] + scn[d];
    int excl = incl - h[bin];
    if (excl < need && need <= incl) { selres[0] = bin; selres[1] = excl; }
  }
  __syncthreads();
}

// ---- K3b: exact top-8192 select via 3-level histogram (11+11+10 bits) ----
// 8 blocks x 1024 threads; keys in registers from sv; writes sparse sp.
__global__ __launch_bounds__(1024) void k_select(const float* __restrict__ y,
                                                 const float* __restrict__ pmm,
                                                 const float* __restrict__ sv,
                                                 const int* __restrict__ ghist,
                                                 float* __restrict__ sp) {
  int b = blockIdx.x;
  int tid = threadIdx.x;
  int wave = tid >> 6, lane = tid & 63;
  __shared__ int h[2048], scn[2048];
  __shared__ int segtot[32], segbase[32];
  __shared__ int selres[2];
  __shared__ int wtot[16];

  int e = tid * 16;
  float s16[16];
  unsigned kk[16];
  #pragma unroll
  for (int q = 0; q < 4; ++q) {
    f32x4 v4 = *(const f32x4*)(sv + b * LL + e + q * 4);
    s16[q * 4 + 0] = v4.x; s16[q * 4 + 1] = v4.y;
    s16[q * 4 + 2] = v4.z; s16[q * 4 + 3] = v4.w;
  }
  #pragma unroll
  for (int i = 0; i < 16; ++i) kk[i] = fkey(s16[i]);

  // round 1: 11-bit global histogram
  h[tid] = ghist[b * 2048 + tid];
  h[1024 + tid] = ghist[b * 2048 + 1024 + tid];
  __syncthreads();
  int need = KLIM;
  desc_pick<2048>(h, scn, segtot, segbase, selres, need, wave, lane);
  unsigned p_hi = (unsigned)selres[0];
  need -= selres[1];

  // round 2: next 11 bits among bucket p_hi
  h[tid] = 0; h[1024 + tid] = 0;
  __syncthreads();
  #pragma unroll
  for (int i = 0; i < 16; ++i)
    if ((kk[i] >> 21) == p_hi) atomicAdd(&h[(kk[i] >> 10) & 0x7FF], 1);
  __syncthreads();
  desc_pick<2048>(h, scn, segtot, segbase, selres, need, wave, lane);
  unsigned p_mid = (unsigned)selres[0];
  need -= selres[1];
  unsigned pfx22 = (p_hi << 11) | p_mid;

  // round 3: last 10 bits among 22-bit prefix match
  h[tid] = 0;
  __syncthreads();
  #pragma unroll
  for (int i = 0; i < 16; ++i)
    if ((kk[i] >> 10) == pfx22) atomicAdd(&h[kk[i] & 0x3FF], 1);
  __syncthreads();
  desc_pick<1024>(h, scn, segtot, segbase, selres, need, wave, lane);
  unsigned p = (pfx22 << 10) | (unsigned)selres[0];
  need -= selres[1];                         // count of equal keys to keep

  // rank equal keys in index order
  int cnt = 0;
  #pragma unroll
  for (int i = 0; i < 16; ++i) cnt += (kk[i] == p);
  int pre = cnt;
  #pragma unroll
  for (int m = 1; m < 64; m <<= 1) {
    int t = __shfl_up(pre, m);
    if (lane >= m) pre += t;
  }
  if (lane == 63) wtot[wave] = pre;
  __syncthreads();
  int base = 0;
  for (int t = 0; t < 16; ++t) if (t < wave) base += wtot[t];
  int rank = base + pre - cnt;

  // output: v from y, gate by selection
  float mn = pmm[b * 32], mx = pmm[b * 32 + 1];
  #pragma unroll
  for (int t = 1; t < 16; ++t) {
    mn = fminf(mn, pmm[b * 32 + t * 2]);
    mx = fmaxf(mx, pmm[b * 32 + t * 2 + 1]);
  }
  float inv = 1.f / (mx - mn);
  float v16[16];
  #pragma unroll
  for (int q = 0; q < 4; ++q) {
    f32x4 y4 = *(const f32x4*)(y + b * LL + e + q * 4);
    v16[q * 4 + 0] = (y4.x - mn) * inv; v16[q * 4 + 1] = (y4.y - mn) * inv;
    v16[q * 4 + 2] = (y4.z - mn) * inv; v16[q * 4 + 3] = (y4.w - mn) * inv;
  }
  float outv[16];
  #pragma unroll
  for (int i = 0; i < 16; ++i) {
    bool sel;
    if (kk[i] > p) sel = true;
    else if (kk[i] == p) { sel = (rank < need); rank++; }
    else sel = false;
    outv[i] = sel ? v16[i] * (sigmoidf(s16[i]) + 1.f) : 0.f;
  }
  float* spb = sp + b * LL + e;
  #pragma unroll
  for (int q = 0; q < 4; ++q)
    *(f32x4*)(spb + q * 4) = *(f32x4*)(outv + q * 4);
}

// ---- K4: split-K GEMM1 partials (R8 body, unchanged) ----
__global__ __launch_bounds__(1024, 4) void k_gemm1(const float* __restrict__ W1,
                                                   const float* __restrict__ sp,
                                                   float* __restrict__ p1) {
  __shared__ float sps[8][2048];            // 64 KB
  int bid = blockIdx.x;
  int s = bid & 7, g = bid >> 3;            // split, row-group
  int tid = threadIdx.x, wave = tid >> 6, lane = tid & 63;
  #pragma unroll
  for (int i = 0; i < 4; ++i) {
    int idx = i * 1024 + tid;               // f32x4 index 0..4095
    int bb = idx >> 9, off = (idx & 511) * 4;
    *(f32x4*)&sps[bb][off] = *(const f32x4*)(sp + (size_t)bb * LL + s * 2048 + off);
  }
  __syncthreads();
  int r0 = g * 94;
  int nr = N1 - r0; if (nr > 94) nr = 94;   // always even (94 or 78)
  int npair = nr >> 1;
  for (int p = wave; p < npair; p += 16) {
    int rA = r0 + p * 2;
    const float* wpA = W1 + (size_t)rA * LL + s * 2048;
    const float* wpB = wpA + LL;
    float acc0[8], acc1[8];
    #pragma unroll
    for (int bb = 0; bb < 8; ++bb) { acc0[bb] = 0.f; acc1[bb] = 0.f; }
    #pragma unroll 2
    for (int it = 0; it < 8; ++it) {
      int k0 = it * 256 + lane * 4;
      f32x4 wA = __builtin_nontemporal_load((const f32x4*)(wpA + k0));
      f32x4 wB = __builtin_nontemporal_load((const f32x4*)(wpB + k0));
      #pragma unroll
      for (int bb = 0; bb < 8; ++bb) {
        f32x4 s4 = *(const f32x4*)&sps[bb][k0];
        acc0[bb] += wA.x * s4.x + wA.y * s4.y + wA.z * s4.z + wA.w * s4.w;
        acc1[bb] += wB.x * s4.x + wB.y * s4.y + wB.z * s4.z + wB.w * s4.w;
      }
    }
    #pragma unroll
    for (int bb = 0; bb < 8; ++bb) {
      float a0 = acc0[bb], a1 = acc1[bb];
      #pragma unroll
      for (int m = 1; m < 64; m <<= 1) {
        a0 += __shfl_xor(a0, m);
        a1 += __shfl_xor(a1, m);
      }
      if (lane == 0) {
        p1[(size_t)(s * 8 + bb) * N1 + rA]     = a0;
        p1[(size_t)(s * 8 + bb) * N1 + rA + 1] = a1;
      }
    }
  }
}

// ---- K5: split-K GEMM2 partials (R8 body; 30-row groups, 3x164 grid) ----
__global__ __launch_bounds__(1024, 4) void k_gemm2(const float* __restrict__ W2,
                                                   const float* __restrict__ p1,
                                                   const float* __restrict__ b1,
                                                   float* __restrict__ p2) {
  __shared__ float hs[8][2048];             // 64 KB
  int bid = blockIdx.x;
  int s = bid / 164, g = bid % 164;
  int ks = s * 2048;
  int klen = (s == 2) ? (N1 - 4096) : 2048; // 1904 for last split
  int tid = threadIdx.x, wave = tid >> 6, lane = tid & 63;
  #pragma unroll
  for (int i = 0; i < 4; ++i) {
    int idx = i * 1024 + tid;               // 0..4095
    int bb = idx >> 9, off = (idx & 511) * 4;
    f32x4 v = {0.f, 0.f, 0.f, 0.f};
    if (off < klen) {
      int j = ks + off;
      #pragma unroll
      for (int q = 0; q < 8; ++q)
        v += *(const f32x4*)(p1 + (size_t)(q * 8 + bb) * N1 + j);
      v += *(const f32x4*)(b1 + j);
    }
    *(f32x4*)&hs[bb][off] = v;
  }
  __syncthreads();
  int r0 = g * 30;
  int nr = N2 - r0; if (nr > 30) nr = 30; if (nr < 0) nr = 0;  // even (30/24)
  int npair = nr >> 1;
  for (int p = wave; p < npair; p += 16) {
    int rA = r0 + p * 2;
    const float* wpA = W2 + (size_t)rA * N1 + ks;
    const float* wpB = wpA + N1;
    float acc0[8], acc1[8];
    #pragma unroll
    for (int bb = 0; bb < 8; ++bb) { acc0[bb] = 0.f; acc1[bb] = 0.f; }
    #pragma unroll 2
    for (int it = 0; it < 8; ++it) {
      int k0 = it * 256 + lane * 4;
      // hs is zero beyond klen, so products vanish; W read stays in-page.
      f32x4 wA = __builtin_nontemporal_load((const f32x4*)(wpA + k0));
      f32x4 wB = __builtin_nontemporal_load((const f32x4*)(wpB + k0));
      #pragma unroll
      for (int bb = 0; bb < 8; ++bb) {
        f32x4 s4 = *(const f32x4*)&hs[bb][k0];
        acc0[bb] += wA.x * s4.x + wA.y * s4.y + wA.z * s4.z + wA.w * s4.w;
        acc1[bb] += wB.x * s4.x + wB.y * s4.y + wB.z * s4.z + wB.w * s4.w;
      }
    }
    #pragma unroll
    for (int bb = 0; bb < 8; ++bb) {
      float a0 = acc0[bb], a1 = acc1[bb];
      #pragma unroll
      for (int m = 1; m < 64; m <<= 1) {
        a0 += __shfl_xor(a0, m);
        a1 += __shfl_xor(a1, m);
      }
      if (lane == 0) {
        p2[(size_t)(s * 8 + bb) * N2 + rA]     = a0;
        p2[(size_t)(s * 8 + bb) * N2 + rA + 1] = a1;
      }
    }
  }
}

// ---- K6: t[b,m] = sum_n h2[b,n]*Wc1[m,n], h2 reconstructed from 3 partials + b2 ----
__global__ void k_cls1(const float* __restrict__ p2, const float* __restrict__ b2,
                       const float* __restrict__ Wc1, float* __restrict__ t) {
  int bid = blockIdx.x; int b = bid >> 5, m = bid & 31;
  int tid = threadIdx.x;
  const float* wm = Wc1 + m * N2;
  float s = 0.f;
  for (int j = tid; j < N2; j += 256) {
    float hv = p2[(size_t)(0 * 8 + b) * N2 + j]
             + p2[(size_t)(1 * 8 + b) * N2 + j]
             + p2[(size_t)(2 * 8 + b) * N2 + j] + b2[j];
    s += hv * wm[j];
  }
  #pragma unroll
  for (int mm = 1; mm < 64; mm <<= 1) s += __shfl_xor(s, mm);
  __shared__ float red[4];
  if ((tid & 63) == 0) red[tid >> 6] = s;
  __syncthreads();
  if (tid == 0) t[b * 32 + m] = red[0] + red[1] + red[2] + red[3];
}

// ---- K7: logits = t @ Wc2^T ; log_softmax ----
__global__ void k_final(const float* __restrict__ t, const float* __restrict__ Wc2,
                        float* __restrict__ out) {
  int b = threadIdx.x;
  if (b < NB) {
    float lg[NCLS];
    #pragma unroll
    for (int k = 0; k < NCLS; ++k) {
      float s = 0.f;
      #pragma unroll
      for (int m = 0; m < 32; ++m) s += t[b * 32 + m] * Wc2[k * 32 + m];
      lg[k] = s;
    }
    float mx = lg[0];
    #pragma unroll
    for (int k = 1; k < NCLS; ++k) mx = fmaxf(mx, lg[k]);
    float se = 0.f;
    #pragma unroll
    for (int k = 0; k < NCLS; ++k) se += expf(lg[k] - mx);
    float lse = logf(se);
    #pragma unroll
    for (int k = 0; k < NCLS; ++k) out[b * NCLS + k] = lg[k] - mx - lse;
  }
}

extern "C" void kernel_launch(void* const* d_in, const int* in_sizes, int n_in,
                              void* d_out, int out_size, void* d_ws, size_t ws_size,
                              hipStream_t stream) {
  const float* adj   = (const float*)d_in[0];
  const float* eca_w = (const float*)d_in[1];
  const float* att_w = (const float*)d_in[2];
  const float* W1    = (const float*)d_in[3];
  const float* b1    = (const float*)d_in[4];
  const float* W2    = (const float*)d_in[5];
  const float* b2    = (const float*)d_in[6];
  const float* Wc1   = (const float*)d_in[7];
  const float* Wc2   = (const float*)d_in[8];
  float* out = (float*)d_out;
  float* ws  = (float*)d_ws;

  float* pooled = ws;              // 240
  float* pmm    = ws + 512;        // 256
  float* tbuf   = ws + 768;        // 256
  float* y      = ws + 1024;       // 131072
  float* sp     = y  + NB * LL;    // 131072 (k_score writes raw scores here; k_select overwrites)
  float* p1     = sp + NB * LL;    // 8*8*6000 = 384000
  float* p2     = p1 + 384000;     // 3*8*4914 = 117936
  int*   ghist  = (int*)(p2 + 117936); // 8*2048 = 16384 ints

  k_pool  <<<NB * NCH, 256, 0, stream>>>(adj, pooled);
  k_wsum  <<<NB * 16, 256, 0, stream>>>(adj, pooled, eca_w, y, pmm, out + NB * NCLS, ghist);
  k_score <<<64, 256, 0, stream>>>(y, pmm, att_w, sp, ghist);
  k_select<<<NB, 1024, 0, stream>>>(y, pmm, sp, ghist, sp);
  k_gemm1 <<<8 * 64, 1024, 0, stream>>>(W1, sp, p1);
  k_gemm2 <<<3 * 164, 1024, 0, stream>>>(W2, p1, b1, p2);
  k_cls1  <<<NB * 32, 256, 0, stream>>>(p2, b2, Wc1, tbuf);
  k_final <<<1, 64, 0, stream>>>(tbuf, Wc2, out);
}